// Round 1
// baseline (2566.698 us; speedup 1.0000x reference)
//
#include <hip/hip_runtime.h>
#include <hip/hip_bf16.h>
#include <cstdint>
#include <cstddef>

#define DEV __device__ __forceinline__

typedef __attribute__((ext_vector_type(8))) short short8;   // 8 bf16 (4 VGPR)
typedef __attribute__((ext_vector_type(4))) float f32x4;
typedef unsigned short u16;
typedef unsigned int u32;

static constexpr int Vv = 50257;
static constexpr int Dd = 768;
static constexpr int Ll = 12;
static constexpr int Hh = 12;
static constexpr int Ff = 3072;
static constexpr int Ss = 1024;
static constexpr int Bbatch = 2;
static constexpr int DHh = 64;
static constexpr int Mtok = Bbatch * Ss;   // 2048
static constexpr int NQKV = 3 * Dd;        // 2304
static constexpr int VPAD = 50304;         // 50257 padded to 128-multiple

DEV float bf2f(u16 u){ u32 x = ((u32)u) << 16; float f; __builtin_memcpy(&f, &x, 4); return f; }
DEV u16 f2bf(float f){ u32 x; __builtin_memcpy(&x, &f, 4); x += 0x7fffu + ((x >> 16) & 1u); return (u16)(x >> 16); }

DEV void gld_lds16(const void* g, void* l){
  __builtin_amdgcn_global_load_lds((const __attribute__((address_space(1))) void*)g,
                                   (__attribute__((address_space(3))) void*)l, 16, 0, 0);
}

// ---------------- embedding ----------------
__global__ void k_embed(const int* __restrict__ ids, const float* __restrict__ tok,
                        const float* __restrict__ pos, float* __restrict__ x){
  int t = blockIdx.x;
  int id = ids[t];
  int s = t & (Ss - 1);
  const float* tr = tok + (size_t)id * Dd;
  const float* pr = pos + (size_t)s * Dd;
  float* xr = x + (size_t)t * Dd;
  for (int c = threadIdx.x; c < Dd; c += blockDim.x) xr[c] = tr[c] + pr[c];
}

// ---------------- layernorm: f32 in -> bf16 out ----------------
__global__ __launch_bounds__(256) void k_ln(const float* __restrict__ x, const float* __restrict__ g,
                                            const float* __restrict__ b, u16* __restrict__ y){
  int row = blockIdx.x, tid = threadIdx.x;
  const float* xr = x + (size_t)row * Dd;
  float v0 = xr[tid], v1 = xr[tid + 256], v2 = xr[tid + 512];
  float s = v0 + v1 + v2, ss = v0 * v0 + v1 * v1 + v2 * v2;
  for (int o = 1; o < 64; o <<= 1){ s += __shfl_xor(s, o, 64); ss += __shfl_xor(ss, o, 64); }
  __shared__ float red[8];
  int w = tid >> 6, l = tid & 63;
  if (l == 0){ red[w] = s; red[w + 4] = ss; }
  __syncthreads();
  s = red[0] + red[1] + red[2] + red[3];
  ss = red[4] + red[5] + red[6] + red[7];
  float mu = s * (1.0f / Dd);
  float var = ss * (1.0f / Dd) - mu * mu;
  float rs = rsqrtf(var + 1e-5f);
  u16* yr = y + (size_t)row * Dd;
  yr[tid]       = f2bf((v0 - mu) * rs * g[tid]       + b[tid]);
  yr[tid + 256] = f2bf((v1 - mu) * rs * g[tid + 256] + b[tid + 256]);
  yr[tid + 512] = f2bf((v2 - mu) * rs * g[tid + 512] + b[tid + 512]);
}

// ---------------- transpose+convert: f32 [R][C] -> bf16 [C][R] ----------------
__global__ void k_transpose(const float* __restrict__ src, u16* __restrict__ dst,
                            int R, int C, long smat, long dmat){
  __shared__ float tile[32][33];
  src += (size_t)blockIdx.z * smat;
  dst += (size_t)blockIdx.z * dmat;
  int c0 = blockIdx.x * 32, r0 = blockIdx.y * 32;
  int tx = threadIdx.x, ty = threadIdx.y;   // 32 x 8
  #pragma unroll
  for (int i = 0; i < 4; i++){
    int r = r0 + ty + i * 8, c = c0 + tx;
    if (c < C) tile[ty + i * 8][tx] = src[(size_t)r * C + c];
  }
  __syncthreads();
  #pragma unroll
  for (int i = 0; i < 4; i++){
    int c = c0 + ty + i * 8, r = r0 + tx;
    if (c < C) dst[(size_t)c * R + r] = f2bf(tile[tx][ty + i * 8]);
  }
}

// ---------------- V slice transpose: qkv v-part [tok][h*64+d] -> vt [bh][d][s] (bf16) ----------------
__global__ void k_vt(const u16* __restrict__ qkv, u16* __restrict__ vt){
  __shared__ u16 tile[32][33];
  int z = blockIdx.z, b = z / Hh, h = z % Hh;
  int d0 = blockIdx.x * 32, s0 = blockIdx.y * 32;
  int tx = threadIdx.x, ty = threadIdx.y;
  #pragma unroll
  for (int i = 0; i < 4; i++){
    int sP = s0 + ty + i * 8;
    tile[ty + i * 8][tx] = qkv[(size_t)(b * Ss + sP) * NQKV + 2 * Dd + h * DHh + d0 + tx];
  }
  __syncthreads();
  #pragma unroll
  for (int i = 0; i < 4; i++){
    int d = d0 + ty + i * 8;
    vt[((size_t)(z * DHh + d)) * Ss + s0 + tx] = tile[tx][ty + i * 8];
  }
}

// ---------------- pack [bq;bk;bv] per layer into [L][2304] ----------------
__global__ void k_biaspack(const float* __restrict__ bq, const float* __restrict__ bk,
                           const float* __restrict__ bv, float* __restrict__ o){
  int i = blockIdx.x * 256 + threadIdx.x;
  int col = i % NQKV, lay = i / NQKV;
  float v = (col < Dd) ? bq[lay * Dd + col]
          : (col < 2 * Dd) ? bk[lay * Dd + col - Dd]
          : bv[lay * Dd + col - 2 * Dd];
  o[i] = v;
}

// ---------------- GEMM: C[M,N] = act(A[M,K](bf16) * Bt[N,K](bf16) + bias) (+res) ----------------
// m97-style: 2x2 waves, BK=32, global_load_lds w16, chunk-XOR-swizzled LDS.
template<int BM, int BN, int ACT, bool RES, bool OUTBF, bool SCALEQ, bool NB, bool HASBIAS>
__global__ __launch_bounds__(256) void k_gemm(const u16* __restrict__ A, const u16* __restrict__ Bt,
                                              const float* __restrict__ bias, const float* __restrict__ res,
                                              float* __restrict__ Cf, u16* __restrict__ Cb,
                                              int Mm, int Nn, int Kk){
  constexpr int HM = BM / 2, HN = BN / 2;
  constexpr int FM = HM / 16, FN = HN / 16;
  __shared__ __align__(16) u16 ldsA[BM * 32];
  __shared__ __align__(16) u16 ldsB[BN * 32];
  int tid = threadIdx.x, wid = tid >> 6, l = tid & 63;
  int wm = wid >> 1, wn = wid & 1;
  int m0 = blockIdx.y * BM, n0 = blockIdx.x * BN;
  int lr = l & 15, lc = l >> 4;
  f32x4 acc[FM][FN];
  #pragma unroll
  for (int i = 0; i < FM; i++)
    #pragma unroll
    for (int j = 0; j < FN; j++) acc[i][j] = (f32x4)0.0f;
  constexpr int nA = (BM * 4) / 256, nB = (BN * 4) / 256;
  for (int k0 = 0; k0 < Kk; k0 += 32){
    #pragma unroll
    for (int i = 0; i < nA; i++){
      int id = i * 256 + tid, row = id >> 2, c = id & 3;
      int cs = c ^ ((row >> 1) & 3);
      gld_lds16(A + (size_t)(m0 + row) * Kk + k0 + cs * 8,
                (char*)ldsA + (size_t)(i * 256 + (wid << 6)) * 16);
    }
    #pragma unroll
    for (int i = 0; i < nB; i++){
      int id = i * 256 + tid, row = id >> 2, c = id & 3;
      int cs = c ^ ((row >> 1) & 3);
      gld_lds16(Bt + (size_t)(n0 + row) * Kk + k0 + cs * 8,
                (char*)ldsB + (size_t)(i * 256 + (wid << 6)) * 16);
    }
    __syncthreads();
    short8 af[FM], bfr[FN];
    #pragma unroll
    for (int i = 0; i < FM; i++){
      int row = wm * HM + i * 16 + lr;
      af[i] = *(const short8*)((const char*)ldsA + row * 64 + ((lc ^ ((row >> 1) & 3)) << 4));
    }
    #pragma unroll
    for (int j = 0; j < FN; j++){
      int row = wn * HN + j * 16 + lr;
      bfr[j] = *(const short8*)((const char*)ldsB + row * 64 + ((lc ^ ((row >> 1) & 3)) << 4));
    }
    #pragma unroll
    for (int i = 0; i < FM; i++)
      #pragma unroll
      for (int j = 0; j < FN; j++)
        acc[i][j] = __builtin_amdgcn_mfma_f32_16x16x32_bf16(af[i], bfr[j], acc[i][j], 0, 0, 0);
    __syncthreads();
  }
  #pragma unroll
  for (int i = 0; i < FM; i++){
    #pragma unroll
    for (int j = 0; j < FN; j++){
      int col = n0 + wn * HN + j * 16 + lr;
      if (NB && col >= Nn) continue;
      float bv = HASBIAS ? bias[col] : 0.0f;
      #pragma unroll
      for (int r = 0; r < 4; r++){
        int row = m0 + wm * HM + i * 16 + lc * 4 + r;
        float v = acc[i][j][r] + bv;
        if (SCALEQ){ if (col < Dd) v *= 0.125f; }           // q /= sqrt(64)
        if (ACT == 1) v = 0.5f * v * (1.0f + erff(v * 0.70710678118f));  // exact GELU
        if (RES) v += res[(size_t)row * Nn + col];
        if (OUTBF) Cb[(size_t)row * Nn + col] = f2bf(v);
        else       Cf[(size_t)row * Nn + col] = v;
      }
    }
  }
}

// ---------------- flash-style causal attention ----------------
// grid: (S/64, B*H). 4 waves, each owns 16 q rows. KV blocks of 64.
__global__ __launch_bounds__(256) void k_attn(const u16* __restrict__ qkv, const u16* __restrict__ vt,
                                              u16* __restrict__ o){
  __shared__ __align__(16) u16 ldsK[64 * 64];
  __shared__ __align__(16) u16 ldsV[64 * 64];
  __shared__ __align__(16) u16 ldsP[4 * 16 * 72];  // per-wave 16 x 64 (rows padded to 144B)
  int iq = blockIdx.x, bh = blockIdx.y, b = bh / Hh, h = bh % Hh;
  int tid = threadIdx.x, wid = tid >> 6, l = tid & 63, lr = l & 15, lc = l >> 4;
  int qrow = b * Ss + iq * 64 + wid * 16 + lr;
  const u16* qp = qkv + (size_t)qrow * NQKV + h * DHh;
  short8 qf[2];
  qf[0] = *(const short8*)(qp + lc * 8);
  qf[1] = *(const short8*)(qp + 32 + lc * 8);
  float mreg[4], lsum[4];
  f32x4 oacc[4];
  #pragma unroll
  for (int r = 0; r < 4; r++){ mreg[r] = -1e30f; lsum[r] = 0.0f; }
  #pragma unroll
  for (int i = 0; i < 4; i++) oacc[i] = (f32x4)0.0f;
  u16* pbase = ldsP + wid * 16 * 72;
  for (int j = 0; j <= iq; j++){
    #pragma unroll
    for (int c = 0; c < 2; c++){
      int id = c * 256 + tid, row = id >> 3, ch = id & 7;
      int cs = ch ^ (row & 7);
      gld_lds16(qkv + (size_t)(b * Ss + j * 64 + row) * NQKV + Dd + h * DHh + cs * 8,
                (char*)ldsK + (size_t)(c * 256 + (wid << 6)) * 16);
      gld_lds16(vt + ((size_t)(bh * DHh + row)) * Ss + j * 64 + cs * 8,
                (char*)ldsV + (size_t)(c * 256 + (wid << 6)) * 16);
    }
    __syncthreads();
    f32x4 sc[4];
    #pragma unroll
    for (int fn = 0; fn < 4; fn++) sc[fn] = (f32x4)0.0f;
    #pragma unroll
    for (int fn = 0; fn < 4; fn++){
      int kv = fn * 16 + lr;
      #pragma unroll
      for (int ks = 0; ks < 2; ks++){
        int ch = ks * 4 + lc;
        short8 kf = *(const short8*)((const char*)ldsK + kv * 128 + ((ch ^ (kv & 7)) << 4));
        sc[fn] = __builtin_amdgcn_mfma_f32_16x16x32_bf16(qf[ks], kf, sc[fn], 0, 0, 0);
      }
    }
    if (j == iq){
      #pragma unroll
      for (int fn = 0; fn < 4; fn++){
        int kv = fn * 16 + lr;
        #pragma unroll
        for (int r = 0; r < 4; r++){
          int qr = wid * 16 + lc * 4 + r;
          if (kv > qr) sc[fn][r] = -1e30f;
        }
      }
    }
    float alpha[4];
    #pragma unroll
    for (int r = 0; r < 4; r++){
      float mx = fmaxf(fmaxf(sc[0][r], sc[1][r]), fmaxf(sc[2][r], sc[3][r]));
      mx = fmaxf(mx, __shfl_xor(mx, 1, 64));
      mx = fmaxf(mx, __shfl_xor(mx, 2, 64));
      mx = fmaxf(mx, __shfl_xor(mx, 4, 64));
      mx = fmaxf(mx, __shfl_xor(mx, 8, 64));
      float mnew = fmaxf(mreg[r], mx);
      alpha[r] = __expf(mreg[r] - mnew);
      mreg[r] = mnew;
      float rsum = 0.0f;
      #pragma unroll
      for (int fn = 0; fn < 4; fn++){
        float p = __expf(sc[fn][r] - mnew);
        sc[fn][r] = p;
        rsum += p;
      }
      rsum += __shfl_xor(rsum, 1, 64);
      rsum += __shfl_xor(rsum, 2, 64);
      rsum += __shfl_xor(rsum, 4, 64);
      rsum += __shfl_xor(rsum, 8, 64);
      lsum[r] = lsum[r] * alpha[r] + rsum;
    }
    #pragma unroll
    for (int fn = 0; fn < 4; fn++)
      #pragma unroll
      for (int r = 0; r < 4; r++)
        pbase[(lc * 4 + r) * 72 + fn * 16 + lr] = f2bf(sc[fn][r]);
    #pragma unroll
    for (int fd = 0; fd < 4; fd++)
      #pragma unroll
      for (int r = 0; r < 4; r++) oacc[fd][r] *= alpha[r];
    short8 pa[2];
    #pragma unroll
    for (int ks = 0; ks < 2; ks++)
      pa[ks] = *(const short8*)((const char*)pbase + lr * 144 + (ks * 4 + lc) * 16);
    #pragma unroll
    for (int fd = 0; fd < 4; fd++){
      int dd = fd * 16 + lr;
      #pragma unroll
      for (int ks = 0; ks < 2; ks++){
        int ch = ks * 4 + lc;
        short8 vf = *(const short8*)((const char*)ldsV + dd * 128 + ((ch ^ (dd & 7)) << 4));
        oacc[fd] = __builtin_amdgcn_mfma_f32_16x16x32_bf16(pa[ks], vf, oacc[fd], 0, 0, 0);
      }
    }
    __syncthreads();
  }
  #pragma unroll
  for (int fd = 0; fd < 4; fd++)
    #pragma unroll
    for (int r = 0; r < 4; r++){
      int row = b * Ss + iq * 64 + wid * 16 + lc * 4 + r;
      o[(size_t)row * Dd + h * DHh + fd * 16 + lr] = f2bf(oacc[fd][r] / lsum[r]);
    }
}

// ---------------- host ----------------
extern "C" void kernel_launch(void* const* d_in, const int* in_sizes, int n_in,
                              void* d_out, int out_size, void* d_ws, size_t ws_size,
                              hipStream_t stream){
  const int*   ids  = (const int*)d_in[0];
  const float* tok  = (const float*)d_in[1];
  const float* pos  = (const float*)d_in[2];
  const float* Wq   = (const float*)d_in[3];
  const float* bq   = (const float*)d_in[4];
  const float* Wk   = (const float*)d_in[5];
  const float* bk   = (const float*)d_in[6];
  const float* Wv   = (const float*)d_in[7];
  const float* bv   = (const float*)d_in[8];
  const float* Wo   = (const float*)d_in[9];
  const float* bo   = (const float*)d_in[10];
  const float* ln1g = (const float*)d_in[11];
  const float* ln1b = (const float*)d_in[12];
  const float* ln2g = (const float*)d_in[13];
  const float* ln2b = (const float*)d_in[14];
  const float* W1   = (const float*)d_in[15];
  const float* b1   = (const float*)d_in[16];
  const float* W2   = (const float*)d_in[17];
  const float* b2   = (const float*)d_in[18];
  const float* lnfg = (const float*)d_in[19];
  const float* lnfb = (const float*)d_in[20];
  const float* Wh   = (const float*)d_in[21];
  float* out = (float*)d_out;

  auto al = [](size_t x){ return (x + 255) & ~(size_t)255; };
  size_t off = 0;
  auto take = [&](size_t bytes){ size_t r = off; off = al(off + bytes); return r; };
  size_t o_x   = take((size_t)Mtok * Dd * 4);
  size_t o_h   = take((size_t)Mtok * Dd * 2);
  size_t o_qkv = take((size_t)Mtok * NQKV * 2);
  size_t o_vt  = take((size_t)Bbatch * Hh * DHh * Ss * 2);
  size_t o_o   = take((size_t)Mtok * Dd * 2);
  size_t o_mid = take((size_t)Mtok * Ff * 2);
  size_t o_bq  = take((size_t)Ll * NQKV * 4);
  size_t o_rot = off;
  size_t o_wqkv, o_wo, o_w1, o_w2, o_wh;
  bool full;
  {
    size_t t = off;
    o_wqkv = t; t = al(t + (size_t)Ll * NQKV * Dd * 2);
    o_wo   = t; t = al(t + (size_t)Ll * Dd * Dd * 2);
    o_w1   = t; t = al(t + (size_t)Ll * Ff * Dd * 2);
    o_w2   = t; t = al(t + (size_t)Ll * Dd * Ff * 2);
    o_wh   = t; t = al(t + (size_t)VPAD * Dd * 2);
    full = (t <= ws_size);
  }
  char* ws = (char*)d_ws;
  float* x    = (float*)(ws + o_x);
  u16*   h    = (u16*)(ws + o_h);
  u16*   qkvb = (u16*)(ws + o_qkv);
  u16*   vtb  = (u16*)(ws + o_vt);
  u16*   ob   = (u16*)(ws + o_o);
  u16*   midb = (u16*)(ws + o_mid);
  float* bqkvp= (float*)(ws + o_bq);
  u16* wqkvT = full ? (u16*)(ws + o_wqkv) : (u16*)(ws + o_rot);
  u16* woT   = full ? (u16*)(ws + o_wo)   : (u16*)(ws + o_rot);
  u16* w1T   = full ? (u16*)(ws + o_w1)   : (u16*)(ws + o_rot);
  u16* w2T   = full ? (u16*)(ws + o_w2)   : (u16*)(ws + o_rot);
  u16* whT   = full ? (u16*)(ws + o_wh)   : (u16*)(ws + o_rot);

  dim3 tb(32, 8);
  auto tpose = [&](const float* src, u16* dst, int R, int C, int nmat, long smat, long dmat){
    k_transpose<<<dim3((C + 31) / 32, R / 32, nmat), tb, 0, stream>>>(src, dst, R, C, smat, dmat);
  };

  k_biaspack<<<(Ll * NQKV) / 256, 256, 0, stream>>>(bq, bk, bv, bqkvp);
  k_embed<<<Mtok, 256, 0, stream>>>(ids, tok, pos, x);

  if (full){
    tpose(Wq, wqkvT,              Dd, Dd, Ll, (long)Dd * Dd, (long)NQKV * Dd);
    tpose(Wk, wqkvT + Dd * Dd,    Dd, Dd, Ll, (long)Dd * Dd, (long)NQKV * Dd);
    tpose(Wv, wqkvT + 2 * Dd * Dd,Dd, Dd, Ll, (long)Dd * Dd, (long)NQKV * Dd);
    tpose(Wo, woT, Dd, Dd, Ll, (long)Dd * Dd, (long)Dd * Dd);
    tpose(W1, w1T, Dd, Ff, Ll, (long)Dd * Ff, (long)Ff * Dd);
    tpose(W2, w2T, Ff, Dd, Ll, (long)Ff * Dd, (long)Dd * Ff);
    tpose(Wh, whT, Dd, Vv, 1, 0, 0);
  }

  auto gemm_qkv = [&](const u16* A, const u16* Bt, const float* bias, u16* Cb){
    k_gemm<128, 128, 0, false, true, true, false, true>
      <<<dim3(NQKV / 128, Mtok / 128), 256, 0, stream>>>(A, Bt, bias, nullptr, nullptr, Cb, Mtok, NQKV, Dd);
  };
  auto gemm_res = [&](const u16* A, const u16* Bt, const float* bias, float* C, int K){
    k_gemm<64, 128, 0, true, false, false, false, true>
      <<<dim3(Dd / 128, Mtok / 64), 256, 0, stream>>>(A, Bt, bias, C, C, nullptr, Mtok, Dd, K);
  };
  auto gemm_ffn1 = [&](const u16* A, const u16* Bt, const float* bias, u16* Cb){
    k_gemm<128, 128, 1, false, true, false, false, true>
      <<<dim3(Ff / 128, Mtok / 128), 256, 0, stream>>>(A, Bt, bias, nullptr, nullptr, Cb, Mtok, Ff, Dd);
  };
  auto gemm_head = [&](const u16* A, const u16* Bt, float* C){
    k_gemm<128, 128, 0, false, false, false, true, false>
      <<<dim3((Vv + 127) / 128, Mtok / 128), 256, 0, stream>>>(A, Bt, nullptr, nullptr, C, nullptr, Mtok, Vv, Dd);
  };

  for (int l = 0; l < Ll; ++l){
    const u16* wqkvL = full ? wqkvT + (size_t)l * NQKV * Dd : wqkvT;
    const u16* woL   = full ? woT   + (size_t)l * Dd * Dd   : woT;
    const u16* w1L   = full ? w1T   + (size_t)l * Ff * Dd   : w1T;
    const u16* w2L   = full ? w2T   + (size_t)l * Dd * Ff   : w2T;
    if (!full){
      tpose(Wq + (size_t)l * Dd * Dd, wqkvT,              Dd, Dd, 1, 0, 0);
      tpose(Wk + (size_t)l * Dd * Dd, wqkvT + Dd * Dd,    Dd, Dd, 1, 0, 0);
      tpose(Wv + (size_t)l * Dd * Dd, wqkvT + 2 * Dd * Dd,Dd, Dd, 1, 0, 0);
    }
    k_ln<<<Mtok, 256, 0, stream>>>(x, ln1g + l * Dd, ln1b + l * Dd, h);
    gemm_qkv(h, wqkvL, bqkvp + l * NQKV, qkvb);
    k_vt<<<dim3(2, 32, Bbatch * Hh), tb, 0, stream>>>(qkvb, vtb);
    k_attn<<<dim3(Ss / 64, Bbatch * Hh), 256, 0, stream>>>(qkvb, vtb, ob);
    if (!full) tpose(Wo + (size_t)l * Dd * Dd, woT, Dd, Dd, 1, 0, 0);
    gemm_res(ob, woL, bo + l * Dd, x, Dd);
    k_ln<<<Mtok, 256, 0, stream>>>(x, ln2g + l * Dd, ln2b + l * Dd, h);
    if (!full) tpose(W1 + (size_t)l * Dd * Ff, w1T, Dd, Ff, 1, 0, 0);
    gemm_ffn1(h, w1L, b1 + l * Ff, midb);
    if (!full) tpose(W2 + (size_t)l * Ff * Dd, w2T, Ff, Dd, 1, 0, 0);
    gemm_res(midb, w2L, b2 + l * Dd, x, Ff);
  }
  k_ln<<<Mtok, 256, 0, stream>>>(x, lnfg, lnfb, h);
  if (!full) tpose(Wh, whT, Dd, Vv, 1, 0, 0);
  gemm_head(h, whT, out);
}

// Round 2
// 2234.814 us; speedup vs baseline: 1.1485x; 1.1485x over previous
//
#include <hip/hip_runtime.h>
#include <hip/hip_bf16.h>
#include <cstdint>
#include <cstddef>

#define DEV __device__ __forceinline__

typedef __attribute__((ext_vector_type(8))) short short8;   // 8 bf16 (4 VGPR)
typedef __attribute__((ext_vector_type(4))) float f32x4;
typedef unsigned short u16;
typedef unsigned int u32;

static constexpr int Vv = 50257;
static constexpr int Dd = 768;
static constexpr int Ll = 12;
static constexpr int Hh = 12;
static constexpr int Ff = 3072;
static constexpr int Ss = 1024;
static constexpr int Bbatch = 2;
static constexpr int DHh = 64;
static constexpr int Mtok = Bbatch * Ss;   // 2048
static constexpr int NQKV = 3 * Dd;        // 2304
static constexpr int VPAD = 50304;         // 50257 padded to 128-multiple

DEV float bf2f(u16 u){ u32 x = ((u32)u) << 16; float f; __builtin_memcpy(&f, &x, 4); return f; }
DEV u16 f2bf(float f){ u32 x; __builtin_memcpy(&x, &f, 4); x += 0x7fffu + ((x >> 16) & 1u); return (u16)(x >> 16); }

DEV void gld_lds16(const void* g, void* l){
  __builtin_amdgcn_global_load_lds((const __attribute__((address_space(1))) void*)g,
                                   (__attribute__((address_space(3))) void*)l, 16, 0, 0);
}

// ---------------- embedding ----------------
__global__ void k_embed(const int* __restrict__ ids, const float* __restrict__ tok,
                        const float* __restrict__ pos, float* __restrict__ x){
  int t = blockIdx.x;
  int id = ids[t];
  int s = t & (Ss - 1);
  const float* tr = tok + (size_t)id * Dd;
  const float* pr = pos + (size_t)s * Dd;
  float* xr = x + (size_t)t * Dd;
  for (int c = threadIdx.x; c < Dd; c += blockDim.x) xr[c] = tr[c] + pr[c];
}

// ---------------- layernorm: f32 in -> bf16 out ----------------
__global__ __launch_bounds__(256) void k_ln(const float* __restrict__ x, const float* __restrict__ g,
                                            const float* __restrict__ b, u16* __restrict__ y){
  int row = blockIdx.x, tid = threadIdx.x;
  const float* xr = x + (size_t)row * Dd;
  float v0 = xr[tid], v1 = xr[tid + 256], v2 = xr[tid + 512];
  float s = v0 + v1 + v2, ss = v0 * v0 + v1 * v1 + v2 * v2;
  for (int o = 1; o < 64; o <<= 1){ s += __shfl_xor(s, o, 64); ss += __shfl_xor(ss, o, 64); }
  __shared__ float red[8];
  int w = tid >> 6, l = tid & 63;
  if (l == 0){ red[w] = s; red[w + 4] = ss; }
  __syncthreads();
  s = red[0] + red[1] + red[2] + red[3];
  ss = red[4] + red[5] + red[6] + red[7];
  float mu = s * (1.0f / Dd);
  float var = ss * (1.0f / Dd) - mu * mu;
  float rs = rsqrtf(var + 1e-5f);
  u16* yr = y + (size_t)row * Dd;
  yr[tid]       = f2bf((v0 - mu) * rs * g[tid]       + b[tid]);
  yr[tid + 256] = f2bf((v1 - mu) * rs * g[tid + 256] + b[tid + 256]);
  yr[tid + 512] = f2bf((v2 - mu) * rs * g[tid + 512] + b[tid + 512]);
}

// ---------------- transpose+convert: f32 [R][C] -> bf16 [C][R] ----------------
__global__ void k_transpose(const float* __restrict__ src, u16* __restrict__ dst,
                            int R, int C, long smat, long dmat){
  __shared__ float tile[32][33];
  src += (size_t)blockIdx.z * smat;
  dst += (size_t)blockIdx.z * dmat;
  int c0 = blockIdx.x * 32, r0 = blockIdx.y * 32;
  int tx = threadIdx.x, ty = threadIdx.y;   // 32 x 8
  #pragma unroll
  for (int i = 0; i < 4; i++){
    int r = r0 + ty + i * 8, c = c0 + tx;
    if (c < C) tile[ty + i * 8][tx] = src[(size_t)r * C + c];
  }
  __syncthreads();
  #pragma unroll
  for (int i = 0; i < 4; i++){
    int c = c0 + ty + i * 8, r = r0 + tx;
    if (c < C) dst[(size_t)c * R + r] = f2bf(tile[tx][ty + i * 8]);
  }
}

// ---------------- V slice transpose: qkv v-part [tok][h*64+d] -> vt [bh][d][s] (bf16) ----------------
__global__ void k_vt(const u16* __restrict__ qkv, u16* __restrict__ vt){
  __shared__ u16 tile[32][33];
  int z = blockIdx.z, b = z / Hh, h = z % Hh;
  int d0 = blockIdx.x * 32, s0 = blockIdx.y * 32;
  int tx = threadIdx.x, ty = threadIdx.y;
  #pragma unroll
  for (int i = 0; i < 4; i++){
    int sP = s0 + ty + i * 8;
    tile[ty + i * 8][tx] = qkv[(size_t)(b * Ss + sP) * NQKV + 2 * Dd + h * DHh + d0 + tx];
  }
  __syncthreads();
  #pragma unroll
  for (int i = 0; i < 4; i++){
    int d = d0 + ty + i * 8;
    vt[((size_t)(z * DHh + d)) * Ss + s0 + tx] = tile[tx][ty + i * 8];
  }
}

// ---------------- pack [bq;bk;bv] per layer into [L][2304] ----------------
__global__ void k_biaspack(const float* __restrict__ bq, const float* __restrict__ bk,
                           const float* __restrict__ bv, float* __restrict__ o){
  int i = blockIdx.x * 256 + threadIdx.x;
  int col = i % NQKV, lay = i / NQKV;
  float v = (col < Dd) ? bq[lay * Dd + col]
          : (col < 2 * Dd) ? bk[lay * Dd + col - Dd]
          : bv[lay * Dd + col - 2 * Dd];
  o[i] = v;
}

// ---------------- combine split-K partials + bias + residual (in-place on x) ----------------
__global__ __launch_bounds__(256) void k_combine(const float* __restrict__ p,
                                                 const float* __restrict__ bias,
                                                 float* __restrict__ x){
  int i = blockIdx.x * 256 + threadIdx.x;          // one float4 group
  f32x4 a  = ((const f32x4*)x)[i];
  f32x4 q0 = ((const f32x4*)p)[i];
  f32x4 q1 = ((const f32x4*)(p + (size_t)Mtok * Dd))[i];
  int col0 = (i * 4) % Dd;
  f32x4 bv = *(const f32x4*)(bias + col0);
  ((f32x4*)x)[i] = a + q0 + q1 + bv;
}

// ---------------- GEMM: C[M,N] = act(A[M,K](bf16) * Bt[N,K](bf16) + bias) (+res) ----------------
// 2-phase double-buffered (T3-minimum), XCD-chunked 1D grid, M-fastest logical order.
template<int BM, int BN, int ACT, bool RES, bool OUTBF, bool SCALEQ, bool NB, bool HASBIAS, bool SPLIT>
__global__ __launch_bounds__(256) void k_gemm(const u16* __restrict__ A, const u16* __restrict__ Bt,
                                              const float* __restrict__ bias, const float* __restrict__ res,
                                              float* __restrict__ Cf, u16* __restrict__ Cb,
                                              int Mm, int Nn, int Kk, int MT, int NT, int KS){
  constexpr int HM = BM / 2, HN = BN / 2;
  constexpr int FM = HM / 16, FN = HN / 16;
  __shared__ __align__(16) u16 ldsA[2][BM * 32];
  __shared__ __align__(16) u16 ldsB[2][BN * 32];
  int tid = threadIdx.x, wid = tid >> 6, l = tid & 63;
  int wm = wid >> 1, wn = wid & 1;
  int lr = l & 15, lc = l >> 4;
  // XCD-chunked bijective swizzle (requires nwg % 8 == 0; all our launches satisfy it)
  int nwg = gridDim.x, dIdx = blockIdx.x;
  int L = ((nwg & 7) == 0) ? ((dIdx & 7) * (nwg >> 3) + (dIdx >> 3)) : dIdx;
  int kidx = 0;
  if (SPLIT){ int per = MT * NT; kidx = L / per; L -= kidx * per; }
  int mtile = L % MT, ntile = L / MT;
  int m0 = mtile * BM, n0 = ntile * BN;
  int klen = Kk / KS, kbase = kidx * klen, nk = klen >> 5;

  f32x4 acc[FM][FN];
  #pragma unroll
  for (int i = 0; i < FM; i++)
    #pragma unroll
    for (int j = 0; j < FN; j++) acc[i][j] = (f32x4)0.0f;

  constexpr int nA = (BM * 4) / 256, nB = (BN * 4) / 256;
  auto stage = [&](int buf, int kk){
    #pragma unroll
    for (int i = 0; i < nA; i++){
      int id = i * 256 + tid, row = id >> 2, c = id & 3;
      int cs = c ^ ((row >> 1) & 3);
      gld_lds16(A + (size_t)(m0 + row) * Kk + kk + cs * 8,
                (char*)ldsA[buf] + (size_t)(i * 256 + (wid << 6)) * 16);
    }
    #pragma unroll
    for (int i = 0; i < nB; i++){
      int id = i * 256 + tid, row = id >> 2, c = id & 3;
      int cs = c ^ ((row >> 1) & 3);
      gld_lds16(Bt + (size_t)(n0 + row) * Kk + kk + cs * 8,
                (char*)ldsB[buf] + (size_t)(i * 256 + (wid << 6)) * 16);
    }
  };
  auto compute = [&](int buf){
    short8 af[FM], bfr[FN];
    #pragma unroll
    for (int i = 0; i < FM; i++){
      int row = wm * HM + i * 16 + lr;
      af[i] = *(const short8*)((const char*)ldsA[buf] + row * 64 + ((lc ^ ((row >> 1) & 3)) << 4));
    }
    #pragma unroll
    for (int j = 0; j < FN; j++){
      int row = wn * HN + j * 16 + lr;
      bfr[j] = *(const short8*)((const char*)ldsB[buf] + row * 64 + ((lc ^ ((row >> 1) & 3)) << 4));
    }
    #pragma unroll
    for (int i = 0; i < FM; i++)
      #pragma unroll
      for (int j = 0; j < FN; j++)
        acc[i][j] = __builtin_amdgcn_mfma_f32_16x16x32_bf16(af[i], bfr[j], acc[i][j], 0, 0, 0);
  };

  stage(0, kbase);
  __syncthreads();                       // drains vmcnt -> buf0 ready
  for (int t = 0; t < nk - 1; ++t){
    stage((t + 1) & 1, kbase + (t + 1) * 32);   // prefetch next tile (overlaps compute)
    compute(t & 1);
    __syncthreads();                     // drains vmcnt+lgkm -> next buf ready, cur buf free
  }
  compute((nk - 1) & 1);

  if (SPLIT){
    float* P = Cf + (size_t)kidx * Mm * Nn;
    #pragma unroll
    for (int i = 0; i < FM; i++)
      #pragma unroll
      for (int j = 0; j < FN; j++){
        int col = n0 + wn * HN + j * 16 + lr;
        #pragma unroll
        for (int r = 0; r < 4; r++){
          int row = m0 + wm * HM + i * 16 + lc * 4 + r;
          P[(size_t)row * Nn + col] = acc[i][j][r];
        }
      }
    return;
  }
  #pragma unroll
  for (int i = 0; i < FM; i++){
    #pragma unroll
    for (int j = 0; j < FN; j++){
      int col = n0 + wn * HN + j * 16 + lr;
      if (NB && col >= Nn) continue;
      float bv = HASBIAS ? bias[col] : 0.0f;
      #pragma unroll
      for (int r = 0; r < 4; r++){
        int row = m0 + wm * HM + i * 16 + lc * 4 + r;
        float v = acc[i][j][r] + bv;
        if (SCALEQ){ if (col < Dd) v *= 0.125f; }           // q /= sqrt(64)
        if (ACT == 1) v = 0.5f * v * (1.0f + erff(v * 0.70710678118f));  // exact GELU
        if (RES) v += res[(size_t)row * Nn + col];
        if (OUTBF) Cb[(size_t)row * Nn + col] = f2bf(v);
        else       Cf[(size_t)row * Nn + col] = v;
      }
    }
  }
}

// ---------------- flash-style causal attention ----------------
// grid: (S/64, B*H). 4 waves, each owns 16 q rows. KV blocks of 64.
__global__ __launch_bounds__(256) void k_attn(const u16* __restrict__ qkv, const u16* __restrict__ vt,
                                              u16* __restrict__ o){
  __shared__ __align__(16) u16 ldsK[64 * 64];
  __shared__ __align__(16) u16 ldsV[64 * 64];
  __shared__ __align__(16) u16 ldsP[4 * 16 * 72];  // per-wave 16 x 64 (rows padded to 144B)
  int iq = blockIdx.x, bh = blockIdx.y, b = bh / Hh, h = bh % Hh;
  int tid = threadIdx.x, wid = tid >> 6, l = tid & 63, lr = l & 15, lc = l >> 4;
  int qrow = b * Ss + iq * 64 + wid * 16 + lr;
  const u16* qp = qkv + (size_t)qrow * NQKV + h * DHh;
  short8 qf[2];
  qf[0] = *(const short8*)(qp + lc * 8);
  qf[1] = *(const short8*)(qp + 32 + lc * 8);
  float mreg[4], lsum[4];
  f32x4 oacc[4];
  #pragma unroll
  for (int r = 0; r < 4; r++){ mreg[r] = -1e30f; lsum[r] = 0.0f; }
  #pragma unroll
  for (int i = 0; i < 4; i++) oacc[i] = (f32x4)0.0f;
  u16* pbase = ldsP + wid * 16 * 72;
  for (int j = 0; j <= iq; j++){
    #pragma unroll
    for (int c = 0; c < 2; c++){
      int id = c * 256 + tid, row = id >> 3, ch = id & 7;
      int cs = ch ^ (row & 7);
      gld_lds16(qkv + (size_t)(b * Ss + j * 64 + row) * NQKV + Dd + h * DHh + cs * 8,
                (char*)ldsK + (size_t)(c * 256 + (wid << 6)) * 16);
      gld_lds16(vt + ((size_t)(bh * DHh + row)) * Ss + j * 64 + cs * 8,
                (char*)ldsV + (size_t)(c * 256 + (wid << 6)) * 16);
    }
    __syncthreads();
    f32x4 sc[4];
    #pragma unroll
    for (int fn = 0; fn < 4; fn++) sc[fn] = (f32x4)0.0f;
    #pragma unroll
    for (int fn = 0; fn < 4; fn++){
      int kv = fn * 16 + lr;
      #pragma unroll
      for (int ks = 0; ks < 2; ks++){
        int ch = ks * 4 + lc;
        short8 kf = *(const short8*)((const char*)ldsK + kv * 128 + ((ch ^ (kv & 7)) << 4));
        sc[fn] = __builtin_amdgcn_mfma_f32_16x16x32_bf16(qf[ks], kf, sc[fn], 0, 0, 0);
      }
    }
    if (j == iq){
      #pragma unroll
      for (int fn = 0; fn < 4; fn++){
        int kv = fn * 16 + lr;
        #pragma unroll
        for (int r = 0; r < 4; r++){
          int qr = wid * 16 + lc * 4 + r;
          if (kv > qr) sc[fn][r] = -1e30f;
        }
      }
    }
    float alpha[4];
    #pragma unroll
    for (int r = 0; r < 4; r++){
      float mx = fmaxf(fmaxf(sc[0][r], sc[1][r]), fmaxf(sc[2][r], sc[3][r]));
      mx = fmaxf(mx, __shfl_xor(mx, 1, 64));
      mx = fmaxf(mx, __shfl_xor(mx, 2, 64));
      mx = fmaxf(mx, __shfl_xor(mx, 4, 64));
      mx = fmaxf(mx, __shfl_xor(mx, 8, 64));
      float mnew = fmaxf(mreg[r], mx);
      alpha[r] = __expf(mreg[r] - mnew);
      mreg[r] = mnew;
      float rsum = 0.0f;
      #pragma unroll
      for (int fn = 0; fn < 4; fn++){
        float p = __expf(sc[fn][r] - mnew);
        sc[fn][r] = p;
        rsum += p;
      }
      rsum += __shfl_xor(rsum, 1, 64);
      rsum += __shfl_xor(rsum, 2, 64);
      rsum += __shfl_xor(rsum, 4, 64);
      rsum += __shfl_xor(rsum, 8, 64);
      lsum[r] = lsum[r] * alpha[r] + rsum;
    }
    #pragma unroll
    for (int fn = 0; fn < 4; fn++)
      #pragma unroll
      for (int r = 0; r < 4; r++)
        pbase[(lc * 4 + r) * 72 + fn * 16 + lr] = f2bf(sc[fn][r]);
    #pragma unroll
    for (int fd = 0; fd < 4; fd++)
      #pragma unroll
      for (int r = 0; r < 4; r++) oacc[fd][r] *= alpha[r];
    short8 pa[2];
    #pragma unroll
    for (int ks = 0; ks < 2; ks++)
      pa[ks] = *(const short8*)((const char*)pbase + lr * 144 + (ks * 4 + lc) * 16);
    #pragma unroll
    for (int fd = 0; fd < 4; fd++){
      int dd = fd * 16 + lr;
      #pragma unroll
      for (int ks = 0; ks < 2; ks++){
        int ch = ks * 4 + lc;
        short8 vf = *(const short8*)((const char*)ldsV + dd * 128 + ((ch ^ (dd & 7)) << 4));
        oacc[fd] = __builtin_amdgcn_mfma_f32_16x16x32_bf16(pa[ks], vf, oacc[fd], 0, 0, 0);
      }
    }
    __syncthreads();
  }
  #pragma unroll
  for (int fd = 0; fd < 4; fd++)
    #pragma unroll
    for (int r = 0; r < 4; r++){
      int row = b * Ss + iq * 64 + wid * 16 + lc * 4 + r;
      o[(size_t)row * Dd + h * DHh + fd * 16 + lr] = f2bf(oacc[fd][r] / lsum[r]);
    }
}

// ---------------- host ----------------
extern "C" void kernel_launch(void* const* d_in, const int* in_sizes, int n_in,
                              void* d_out, int out_size, void* d_ws, size_t ws_size,
                              hipStream_t stream){
  const int*   ids  = (const int*)d_in[0];
  const float* tok  = (const float*)d_in[1];
  const float* pos  = (const float*)d_in[2];
  const float* Wq   = (const float*)d_in[3];
  const float* bq   = (const float*)d_in[4];
  const float* Wk   = (const float*)d_in[5];
  const float* bk   = (const float*)d_in[6];
  const float* Wv   = (const float*)d_in[7];
  const float* bv   = (const float*)d_in[8];
  const float* Wo   = (const float*)d_in[9];
  const float* bo   = (const float*)d_in[10];
  const float* ln1g = (const float*)d_in[11];
  const float* ln1b = (const float*)d_in[12];
  const float* ln2g = (const float*)d_in[13];
  const float* ln2b = (const float*)d_in[14];
  const float* W1   = (const float*)d_in[15];
  const float* b1   = (const float*)d_in[16];
  const float* W2   = (const float*)d_in[17];
  const float* b2   = (const float*)d_in[18];
  const float* lnfg = (const float*)d_in[19];
  const float* lnfb = (const float*)d_in[20];
  const float* Wh   = (const float*)d_in[21];
  float* out = (float*)d_out;

  auto al = [](size_t x){ return (x + 255) & ~(size_t)255; };
  size_t off = 0;
  auto take = [&](size_t bytes){ size_t r = off; off = al(off + bytes); return r; };
  size_t o_x    = take((size_t)Mtok * Dd * 4);
  size_t o_h    = take((size_t)Mtok * Dd * 2);
  size_t o_qkv  = take((size_t)Mtok * NQKV * 2);
  size_t o_vt   = take((size_t)Bbatch * Hh * DHh * Ss * 2);
  size_t o_o    = take((size_t)Mtok * Dd * 2);
  size_t o_mid  = take((size_t)Mtok * Ff * 2);
  size_t o_bq   = take((size_t)Ll * NQKV * 4);
  size_t o_part = take((size_t)2 * Mtok * Dd * 4);
  size_t o_rot = off;
  size_t o_wqkv, o_wo, o_w1, o_w2, o_wh;
  bool full;
  {
    size_t t = off;
    o_wqkv = t; t = al(t + (size_t)Ll * NQKV * Dd * 2);
    o_wo   = t; t = al(t + (size_t)Ll * Dd * Dd * 2);
    o_w1   = t; t = al(t + (size_t)Ll * Ff * Dd * 2);
    o_w2   = t; t = al(t + (size_t)Ll * Dd * Ff * 2);
    o_wh   = t; t = al(t + (size_t)VPAD * Dd * 2);
    full = (t <= ws_size);
  }
  char* ws = (char*)d_ws;
  float* x    = (float*)(ws + o_x);
  u16*   h    = (u16*)(ws + o_h);
  u16*   qkvb = (u16*)(ws + o_qkv);
  u16*   vtb  = (u16*)(ws + o_vt);
  u16*   ob   = (u16*)(ws + o_o);
  u16*   midb = (u16*)(ws + o_mid);
  float* bqkvp= (float*)(ws + o_bq);
  float* part = (float*)(ws + o_part);
  u16* wqkvT = full ? (u16*)(ws + o_wqkv) : (u16*)(ws + o_rot);
  u16* woT   = full ? (u16*)(ws + o_wo)   : (u16*)(ws + o_rot);
  u16* w1T   = full ? (u16*)(ws + o_w1)   : (u16*)(ws + o_rot);
  u16* w2T   = full ? (u16*)(ws + o_w2)   : (u16*)(ws + o_rot);
  u16* whT   = full ? (u16*)(ws + o_wh)   : (u16*)(ws + o_rot);

  dim3 tb(32, 8);
  auto tpose = [&](const float* src, u16* dst, int R, int C, int nmat, long smat, long dmat){
    k_transpose<<<dim3((C + 31) / 32, R / 32, nmat), tb, 0, stream>>>(src, dst, R, C, smat, dmat);
  };

  k_biaspack<<<(Ll * NQKV) / 256, 256, 0, stream>>>(bq, bk, bv, bqkvp);
  k_embed<<<Mtok, 256, 0, stream>>>(ids, tok, pos, x);

  if (full){
    tpose(Wq, wqkvT,              Dd, Dd, Ll, (long)Dd * Dd, (long)NQKV * Dd);
    tpose(Wk, wqkvT + Dd * Dd,    Dd, Dd, Ll, (long)Dd * Dd, (long)NQKV * Dd);
    tpose(Wv, wqkvT + 2 * Dd * Dd,Dd, Dd, Ll, (long)Dd * Dd, (long)NQKV * Dd);
    tpose(Wo, woT, Dd, Dd, Ll, (long)Dd * Dd, (long)Dd * Dd);
    tpose(W1, w1T, Dd, Ff, Ll, (long)Dd * Ff, (long)Ff * Dd);
    tpose(W2, w2T, Ff, Dd, Ll, (long)Ff * Dd, (long)Dd * Ff);
    tpose(Wh, whT, Dd, Vv, 1, 0, 0);
  }

  // all grids are 1D, nwg % 8 == 0 for the XCD swizzle
  auto gemm_qkv = [&](const u16* A, const u16* Bt, const float* bias, u16* Cb){
    constexpr int MT = Mtok / 64, NT = NQKV / 128;          // 32 x 18 = 576
    k_gemm<64, 128, 0, false, true, true, false, true, false>
      <<<MT * NT, 256, 0, stream>>>(A, Bt, bias, nullptr, nullptr, Cb, Mtok, NQKV, Dd, MT, NT, 1);
  };
  auto gemm_wo = [&](const u16* A, const u16* Bt, const float* bias, float* C){
    constexpr int MT = Mtok / 64, NT = Dd / 64;             // 32 x 12 = 384
    k_gemm<64, 64, 0, true, false, false, false, true, false>
      <<<MT * NT, 256, 0, stream>>>(A, Bt, bias, C, C, nullptr, Mtok, Dd, Dd, MT, NT, 1);
  };
  auto gemm_ffn1 = [&](const u16* A, const u16* Bt, const float* bias, u16* Cb){
    constexpr int MT = Mtok / 64, NT = Ff / 128;            // 32 x 24 = 768
    k_gemm<64, 128, 1, false, true, false, false, true, false>
      <<<MT * NT, 256, 0, stream>>>(A, Bt, bias, nullptr, nullptr, Cb, Mtok, Ff, Dd, MT, NT, 1);
  };
  auto gemm_ffn2 = [&](const u16* A, const u16* Bt){
    constexpr int MT = Mtok / 64, NT = Dd / 64;             // 32 x 12 x 2 = 768
    k_gemm<64, 64, 0, false, false, false, false, false, true>
      <<<MT * NT * 2, 256, 0, stream>>>(A, Bt, nullptr, nullptr, part, nullptr, Mtok, Dd, Ff, MT, NT, 2);
  };
  auto gemm_head = [&](const u16* A, const u16* Bt, float* C){
    constexpr int MT = Mtok / 128, NT = VPAD / 128;         // 16 x 393 = 6288
    k_gemm<128, 128, 0, false, false, false, true, false, false>
      <<<MT * NT, 256, 0, stream>>>(A, Bt, nullptr, nullptr, C, nullptr, Mtok, Vv, Dd, MT, NT, 1);
  };

  for (int l = 0; l < Ll; ++l){
    const u16* wqkvL = full ? wqkvT + (size_t)l * NQKV * Dd : wqkvT;
    const u16* woL   = full ? woT   + (size_t)l * Dd * Dd   : woT;
    const u16* w1L   = full ? w1T   + (size_t)l * Ff * Dd   : w1T;
    const u16* w2L   = full ? w2T   + (size_t)l * Dd * Ff   : w2T;
    if (!full){
      tpose(Wq + (size_t)l * Dd * Dd, wqkvT,              Dd, Dd, 1, 0, 0);
      tpose(Wk + (size_t)l * Dd * Dd, wqkvT + Dd * Dd,    Dd, Dd, 1, 0, 0);
      tpose(Wv + (size_t)l * Dd * Dd, wqkvT + 2 * Dd * Dd,Dd, Dd, 1, 0, 0);
    }
    k_ln<<<Mtok, 256, 0, stream>>>(x, ln1g + l * Dd, ln1b + l * Dd, h);
    gemm_qkv(h, wqkvL, bqkvp + l * NQKV, qkvb);
    k_vt<<<dim3(2, 32, Bbatch * Hh), tb, 0, stream>>>(qkvb, vtb);
    k_attn<<<dim3(Ss / 64, Bbatch * Hh), 256, 0, stream>>>(qkvb, vtb, ob);
    if (!full) tpose(Wo + (size_t)l * Dd * Dd, woT, Dd, Dd, 1, 0, 0);
    gemm_wo(ob, woL, bo + l * Dd, x);
    k_ln<<<Mtok, 256, 0, stream>>>(x, ln2g + l * Dd, ln2b + l * Dd, h);
    if (!full) tpose(W1 + (size_t)l * Dd * Ff, w1T, Dd, Ff, 1, 0, 0);
    gemm_ffn1(h, w1L, b1 + l * Ff, midb);
    if (!full) tpose(W2 + (size_t)l * Ff * Dd, w2T, Ff, Dd, 1, 0, 0);
    gemm_ffn2(midb, w2L);
    k_combine<<<(Mtok * Dd / 4) / 256, 256, 0, stream>>>(part, b2 + l * Dd, x);
  }
  k_ln<<<Mtok, 256, 0, stream>>>(x, lnfg, lnfb, h);
  if (!full) tpose(Wh, whT, Dd, Vv, 1, 0, 0);
  gemm_head(h, whT, out);
}